// Round 4
// baseline (105.378 us; speedup 1.0000x reference)
//
#include <hip/hip_runtime.h>

#define T_MAX 1024
#define N_NODES 512
#define FEAT 512
#define BATCH_B 4

// Two waves per (b, t): wave-half h owns features [h*256, h*256+256).
// Each lane owns one float4. Block = 256 threads = 4 waves = 2 tokens.
// Span scan per wave: 8 ballot rounds (64 nodes each); matched nodes walked
// in ascending order from the wave-uniform ballot mask (deterministic,
// reference-order accumulation; no atomics, no LDS, no __syncthreads).
__global__ __launch_bounds__(256) void node_embed_kernel(
    const int* __restrict__ tokens,        // [B*T]
    const int* __restrict__ starts,        // [B*N]
    const int* __restrict__ ends,          // [B*N]
    const float* __restrict__ embed_tok,   // [VOCAB, F]
    const float* __restrict__ embed_node,  // [N, F]
    const float* __restrict__ pos_emb,     // [T, F]
    float* __restrict__ out)               // [B*T, F]
{
    const int wave = threadIdx.x >> 6;     // 0..3
    const int lane = threadIdx.x & 63;
    const int bt   = blockIdx.x * 2 + (wave >> 1);  // 0 .. B*T-1
    const int half = wave & 1;                      // which 256-feature half
    const int b    = bt >> 10;
    const int t    = bt & (T_MAX - 1);

    const int tok = tokens[bt];
    const int f   = half * 256 + lane * 4;

    float4 acc = *reinterpret_cast<const float4*>(embed_tok + (size_t)tok * FEAT + f);
    const float4 pe = *reinterpret_cast<const float4*>(pos_emb + (size_t)t * FEAT + f);
    acc.x += pe.x; acc.y += pe.y; acc.z += pe.z; acc.w += pe.w;

    const int* __restrict__ sb = starts + b * N_NODES;
    const int* __restrict__ eb = ends   + b * N_NODES;

    #pragma unroll
    for (int r = 0; r < N_NODES / 64; ++r) {
        const int n = (r << 6) + lane;
        const int s = sb[n];
        const int e = eb[n];
        unsigned long long m = __ballot(s <= t && t <= e);
        // Wave-uniform mask: all lanes walk the same bits, ascending n.
        while (m) {
            const int bit = __builtin_ctzll(m);
            m &= m - 1;
            const float4 v = *reinterpret_cast<const float4*>(
                embed_node + (size_t)((r << 6) + bit) * FEAT + f);
            acc.x += v.x; acc.y += v.y; acc.z += v.z; acc.w += v.w;
        }
    }

    *reinterpret_cast<float4*>(out + (size_t)bt * FEAT + f) = acc;
}

extern "C" void kernel_launch(void* const* d_in, const int* in_sizes, int n_in,
                              void* d_out, int out_size, void* d_ws, size_t ws_size,
                              hipStream_t stream) {
    const int*   tokens     = (const int*)d_in[0];
    const int*   starts     = (const int*)d_in[1];
    const int*   ends       = (const int*)d_in[2];
    const float* embed_tok  = (const float*)d_in[3];
    const float* embed_node = (const float*)d_in[4];
    const float* pos_emb    = (const float*)d_in[5];
    float*       out        = (float*)d_out;

    // 2 tokens per block, 2 waves per token.
    node_embed_kernel<<<dim3(BATCH_B * T_MAX / 2), dim3(256), 0, stream>>>(
        tokens, starts, ends, embed_tok, embed_node, pos_emb, out);
}